// Round 1
// baseline (85.995 us; speedup 1.0000x reference)
//
#include <hip/hip_runtime.h>
#include <math.h>

#define NN 1000
#define LOG2E  1.4426950408889634f
#define LN2PI  1.8378770664093453f   /* log(2*pi) */

__global__ __launch_bounds__(256) void splat_kernel(
    const float* __restrict__ rho, const float* __restrict__ sigma,
    const float* __restrict__ coords, const float* __restrict__ alpha,
    const float* __restrict__ colors, const float* __restrict__ xy,
    float* __restrict__ out)
{
    // LDS: per-gaussian derived params, 12 floats (3x float4) per gaussian.
    // [0]: cx, cy, A, B   [1]: C, K, alpha, colR   [2]: colG, colB, -, -
    __shared__ float4 g[NN][3];

    const int tid = threadIdx.x;

    // ---- per-block redundant precompute of gaussian params into LDS ----
    for (int n = tid; n < NN; n += 256) {
        float sx = tanhf(sigma[2*n]   * 0.5f) + 1e-4f;
        float sy = tanhf(sigma[2*n+1] * 0.5f) + 1e-4f;
        float r  = 1.0f / (1.0f + expf(-rho[n])) + 1e-6f;   // sigmoid + EPS
        float cxx = sx*sx + 1e-6f;
        float cyy = sy*sy + 1e-6f;
        float cxy = sx*sy*r;
        float det = cxx*cyy - cxy*cxy;
        float invdet = 1.0f / det;
        // z = A*dx^2 + B*dy^2 + C*dx*dy  (already scaled by log2(e))
        float A = -0.5f * cyy * invdet * LOG2E;
        float B = -0.5f * cxx * invdet * LOG2E;
        float C =         cxy * invdet * LOG2E;
        float K = (0.5f * logf(det + 1e-6f) - LN2PI) * LOG2E;
        float cx = tanhf(coords[2*n])   - 0.5f;
        float cy = tanhf(coords[2*n+1]) - 0.5f;
        float al = 1.0f / (1.0f + expf(-alpha[n]));
        float cr = 1.0f / (1.0f + expf(-colors[3*n]));
        float cg = 1.0f / (1.0f + expf(-colors[3*n+1]));
        float cb = 1.0f / (1.0f + expf(-colors[3*n+2]));
        g[n][0] = make_float4(cx, cy, A, B);
        g[n][1] = make_float4(C, K, al, cr);
        g[n][2] = make_float4(cg, cb, 0.f, 0.f);
    }
    __syncthreads();

    // ---- one pixel per thread, online-max single pass over gaussians ----
    const int p = blockIdx.x * 256 + tid;
    const float x = xy[2*p];
    const float y = xy[2*p+1];

    float m  = -INFINITY;
    float sa = 0.f, sr = 0.f, sg = 0.f, sb = 0.f;

    #pragma unroll 4
    for (int n = 0; n < NN; ++n) {
        float4 v0 = g[n][0];
        float4 v1 = g[n][1];
        float4 v2 = g[n][2];
        float dx = x + v0.x;
        float dy = y + v0.y;
        float k  = fmaf(v0.z, dx*dx, fmaf(v0.w, dy*dy, fmaf(v1.x, dx*dy, v1.y)));
        // wave-uniform rescale branch (rare after warm-up)
        if (__any(k > m)) {
            float mn = fmaxf(m, k);
            float s  = __builtin_amdgcn_exp2f(m - mn);  // 0 on first hit (m=-inf)
            sa *= s; sr *= s; sg *= s; sb *= s;
            m = mn;
        }
        float e = __builtin_amdgcn_exp2f(k - m);
        sa = fmaf(e, v1.z, sa);
        sr = fmaf(e, v1.w, sr);
        sg = fmaf(e, v2.x, sg);
        sb = fmaf(e, v2.y, sb);
    }

    float inv = 1.0f / (sa + 1e-6f);
    out[3*p]   = sr * inv;
    out[3*p+1] = sg * inv;
    out[3*p+2] = sb * inv;
}

extern "C" void kernel_launch(void* const* d_in, const int* in_sizes, int n_in,
                              void* d_out, int out_size, void* d_ws, size_t ws_size,
                              hipStream_t stream) {
    const float* rho    = (const float*)d_in[0];
    const float* sigma  = (const float*)d_in[1];
    const float* coords = (const float*)d_in[2];
    const float* alpha  = (const float*)d_in[3];
    const float* colors = (const float*)d_in[4];
    const float* xy     = (const float*)d_in[5];
    float* out = (float*)d_out;

    // P = 65536 pixels -> 256 blocks x 256 threads (1 pixel/thread)
    splat_kernel<<<256, 256, 0, stream>>>(rho, sigma, coords, alpha, colors, xy, out);
}

// Round 2
// 66.429 us; speedup vs baseline: 1.2945x; 1.2945x over previous
//
#include <hip/hip_runtime.h>
#include <math.h>

#define NN 1000
#define SPLIT 4
#define GPW 250                      /* gaussians per wave chunk */
#define LOG2E  1.4426950408889634f
#define LN2PI  1.8378770664093453f   /* log(2*pi) */

// ---- kernel 1: per-gaussian derived params -> ws as float4[NN][3] ----
// [0]: cx, cy, A, B   [1]: C, K, alpha, colR   [2]: colG, colB, -, -
__global__ __launch_bounds__(256) void splat_prep(
    const float* __restrict__ rho, const float* __restrict__ sigma,
    const float* __restrict__ coords, const float* __restrict__ alpha,
    const float* __restrict__ colors, float4* __restrict__ gp)
{
    int n = blockIdx.x * 256 + threadIdx.x;
    if (n >= NN) return;
    float sx = tanhf(sigma[2*n]   * 0.5f) + 1e-4f;
    float sy = tanhf(sigma[2*n+1] * 0.5f) + 1e-4f;
    float r  = 1.0f / (1.0f + expf(-rho[n])) + 1e-6f;   // sigmoid + EPS
    float cxx = sx*sx + 1e-6f;
    float cyy = sy*sy + 1e-6f;
    float cxy = sx*sy*r;
    float det = cxx*cyy - cxy*cxy;
    float invdet = 1.0f / det;
    // k = A*dx^2 + B*dy^2 + C*dx*dy + K  (pre-scaled by log2(e))
    float A = -0.5f * cyy * invdet * LOG2E;
    float B = -0.5f * cxx * invdet * LOG2E;
    float C =         cxy * invdet * LOG2E;
    float K = (0.5f * logf(det + 1e-6f) - LN2PI) * LOG2E;
    float cx = tanhf(coords[2*n])   - 0.5f;
    float cy = tanhf(coords[2*n+1]) - 0.5f;
    float al = 1.0f / (1.0f + expf(-alpha[n]));
    float cr = 1.0f / (1.0f + expf(-colors[3*n]));
    float cg = 1.0f / (1.0f + expf(-colors[3*n+1]));
    float cb = 1.0f / (1.0f + expf(-colors[3*n+2]));
    gp[3*n+0] = make_float4(cx, cy, A, B);
    gp[3*n+1] = make_float4(C, K, al, cr);
    gp[3*n+2] = make_float4(cg, cb, 0.f, 0.f);
}

// ---- kernel 2: 64 pixels/block, 4 waves each own a 250-gaussian chunk ----
__global__ __launch_bounds__(256, 4) void splat_main(
    const float4* __restrict__ gp, const float* __restrict__ xy,
    float* __restrict__ out)
{
    const int tid  = threadIdx.x;
    const int wave = __builtin_amdgcn_readfirstlane(tid >> 6);
    const int lane = tid & 63;
    const int p    = blockIdx.x * 64 + lane;

    const float x = xy[2*p];
    const float y = xy[2*p+1];

    float m  = -INFINITY;
    float sa = 0.f, sr = 0.f, sg = 0.f, sb = 0.f;

    const float4* gw = gp + wave * (3*GPW);   // wave-uniform base
    #pragma unroll 5
    for (int i = 0; i < GPW; ++i) {
        float4 v0 = gw[3*i+0];
        float4 v1 = gw[3*i+1];
        float4 v2 = gw[3*i+2];
        float dx = x + v0.x;
        float dy = y + v0.y;
        float k  = fmaf(v0.z, dx*dx, fmaf(v0.w, dy*dy, fmaf(v1.x, dx*dy, v1.y)));
        if (__any(k > m)) {                    // wave-uniform rescale (rare)
            float mn = fmaxf(m, k);
            float s  = __builtin_amdgcn_exp2f(m - mn);
            sa *= s; sr *= s; sg *= s; sb *= s;
            m = mn;
        }
        float e = __builtin_amdgcn_exp2f(k - m);
        sa = fmaf(e, v1.z, sa);
        sr = fmaf(e, v1.w, sr);
        sg = fmaf(e, v2.x, sg);
        sb = fmaf(e, v2.y, sb);
    }

    // ---- combine the 4 per-wave partial softmax states in LDS ----
    __shared__ float part[5][SPLIT][64];
    part[0][wave][lane] = m;
    part[1][wave][lane] = sa;
    part[2][wave][lane] = sr;
    part[3][wave][lane] = sg;
    part[4][wave][lane] = sb;
    __syncthreads();

    if (tid < 64) {
        float M = fmaxf(fmaxf(part[0][0][tid], part[0][1][tid]),
                        fmaxf(part[0][2][tid], part[0][3][tid]));
        float A = 0.f, R = 0.f, G = 0.f, B = 0.f;
        #pragma unroll
        for (int w = 0; w < SPLIT; ++w) {
            float s = __builtin_amdgcn_exp2f(part[0][w][tid] - M);
            A = fmaf(part[1][w][tid], s, A);
            R = fmaf(part[2][w][tid], s, R);
            G = fmaf(part[3][w][tid], s, G);
            B = fmaf(part[4][w][tid], s, B);
        }
        float inv = 1.0f / (A + 1e-6f);
        int q = blockIdx.x * 64 + tid;
        out[3*q]   = R * inv;
        out[3*q+1] = G * inv;
        out[3*q+2] = B * inv;
    }
}

extern "C" void kernel_launch(void* const* d_in, const int* in_sizes, int n_in,
                              void* d_out, int out_size, void* d_ws, size_t ws_size,
                              hipStream_t stream) {
    const float* rho    = (const float*)d_in[0];
    const float* sigma  = (const float*)d_in[1];
    const float* coords = (const float*)d_in[2];
    const float* alpha  = (const float*)d_in[3];
    const float* colors = (const float*)d_in[4];
    const float* xy     = (const float*)d_in[5];
    float* out = (float*)d_out;
    float4* gp = (float4*)d_ws;   // 1000 * 3 * 16 B = 48 KB scratch

    splat_prep<<<(NN + 255) / 256, 256, 0, stream>>>(rho, sigma, coords, alpha, colors, gp);
    // 65536 px / 64 px-per-block = 1024 blocks; 4 waves/block, one N-chunk each
    splat_main<<<65536 / 64, 256, 0, stream>>>(gp, xy, out);
}

// Round 3
// 38.061 us; speedup vs baseline: 2.2594x; 1.7453x over previous
//
#include <hip/hip_runtime.h>
#include <math.h>

#define NN 1000
#define SPLIT 8
#define GPW 125                      /* gaussians per wave chunk */
#define BATCH 5
#define LOG2E  1.4426950408889634f
#define LN2PI  1.8378770664093453f   /* log(2*pi) */

// ---- kernel 1: per-gaussian derived params -> ws as float4[NN][3] ----
// [0]: cx, cy, A, B   [1]: C, K, alpha, colR   [2]: colG, colB, -, -
__global__ __launch_bounds__(256) void splat_prep(
    const float* __restrict__ rho, const float* __restrict__ sigma,
    const float* __restrict__ coords, const float* __restrict__ alpha,
    const float* __restrict__ colors, float4* __restrict__ gp)
{
    int n = blockIdx.x * 256 + threadIdx.x;
    if (n >= NN) return;
    float sx = tanhf(sigma[2*n]   * 0.5f) + 1e-4f;
    float sy = tanhf(sigma[2*n+1] * 0.5f) + 1e-4f;
    float r  = 1.0f / (1.0f + expf(-rho[n])) + 1e-6f;   // sigmoid + EPS
    float cxx = sx*sx + 1e-6f;
    float cyy = sy*sy + 1e-6f;
    float cxy = sx*sy*r;
    float det = cxx*cyy - cxy*cxy;
    float invdet = 1.0f / det;
    // k = A*dx^2 + B*dy^2 + C*dx*dy + K  (pre-scaled by log2(e))
    float A = -0.5f * cyy * invdet * LOG2E;
    float B = -0.5f * cxx * invdet * LOG2E;
    float C =         cxy * invdet * LOG2E;
    float K = (0.5f * logf(det + 1e-6f) - LN2PI) * LOG2E;
    float cx = tanhf(coords[2*n])   - 0.5f;
    float cy = tanhf(coords[2*n+1]) - 0.5f;
    float al = 1.0f / (1.0f + expf(-alpha[n]));
    float cr = 1.0f / (1.0f + expf(-colors[3*n]));
    float cg = 1.0f / (1.0f + expf(-colors[3*n+1]));
    float cb = 1.0f / (1.0f + expf(-colors[3*n+2]));
    gp[3*n+0] = make_float4(cx, cy, A, B);
    gp[3*n+1] = make_float4(C, K, al, cr);
    gp[3*n+2] = make_float4(cg, cb, 0.f, 0.f);
}

// ---- kernel 2: 64 pixels/block, 8 waves each own a 125-gaussian chunk ----
__global__ __launch_bounds__(512, 8) void splat_main(
    const float4* __restrict__ gp, const float* __restrict__ xy,
    float* __restrict__ out)
{
    const int tid  = threadIdx.x;
    const int wave = __builtin_amdgcn_readfirstlane(tid >> 6);
    const int lane = tid & 63;
    const int p    = blockIdx.x * 64 + lane;

    const float x = xy[2*p];
    const float y = xy[2*p+1];

    float m  = -INFINITY;
    float sa = 0.f, sr = 0.f, sg = 0.f, sb = 0.f;

    const float4* gw = gp + wave * (3*GPW);   // wave-uniform base
    for (int b = 0; b < GPW; b += BATCH) {
        // batched scalar loads (one basic block -> pipelineable)
        float4 v0[BATCH], v1[BATCH], v2[BATCH];
        #pragma unroll
        for (int j = 0; j < BATCH; ++j) {
            v0[j] = gw[3*(b+j)+0];
            v1[j] = gw[3*(b+j)+1];
            v2[j] = gw[3*(b+j)+2];
        }
        // branch-free k for the whole batch + batch max
        float k[BATCH];
        float kb = -INFINITY;
        #pragma unroll
        for (int j = 0; j < BATCH; ++j) {
            float dx = x + v0[j].x;
            float dy = y + v0[j].y;
            k[j] = fmaf(v0[j].z, dx*dx, fmaf(v0[j].w, dy*dy, fmaf(v1[j].x, dx*dy, v1[j].y)));
            kb = fmaxf(kb, k[j]);
        }
        // one uniform rescale branch per batch (rarely taken after warm-up)
        if (__any(kb > m)) {
            float mn = fmaxf(m, kb);
            float s  = __builtin_amdgcn_exp2f(m - mn);  // 0 on first hit (m=-inf)
            sa *= s; sr *= s; sg *= s; sb *= s;
            m = mn;
        }
        #pragma unroll
        for (int j = 0; j < BATCH; ++j) {
            float e = __builtin_amdgcn_exp2f(k[j] - m);
            sa = fmaf(e, v1[j].z, sa);
            sr = fmaf(e, v1[j].w, sr);
            sg = fmaf(e, v2[j].x, sg);
            sb = fmaf(e, v2[j].y, sb);
        }
    }

    // ---- combine the 8 per-wave partial softmax states in LDS ----
    __shared__ float part[5][SPLIT][64];
    part[0][wave][lane] = m;
    part[1][wave][lane] = sa;
    part[2][wave][lane] = sr;
    part[3][wave][lane] = sg;
    part[4][wave][lane] = sb;
    __syncthreads();

    if (tid < 64) {
        float M = part[0][0][tid];
        #pragma unroll
        for (int w = 1; w < SPLIT; ++w) M = fmaxf(M, part[0][w][tid]);
        float A = 0.f, R = 0.f, G = 0.f, B = 0.f;
        #pragma unroll
        for (int w = 0; w < SPLIT; ++w) {
            float s = __builtin_amdgcn_exp2f(part[0][w][tid] - M);
            A = fmaf(part[1][w][tid], s, A);
            R = fmaf(part[2][w][tid], s, R);
            G = fmaf(part[3][w][tid], s, G);
            B = fmaf(part[4][w][tid], s, B);
        }
        float inv = 1.0f / (A + 1e-6f);
        int q = blockIdx.x * 64 + tid;
        out[3*q]   = R * inv;
        out[3*q+1] = G * inv;
        out[3*q+2] = B * inv;
    }
}

extern "C" void kernel_launch(void* const* d_in, const int* in_sizes, int n_in,
                              void* d_out, int out_size, void* d_ws, size_t ws_size,
                              hipStream_t stream) {
    const float* rho    = (const float*)d_in[0];
    const float* sigma  = (const float*)d_in[1];
    const float* coords = (const float*)d_in[2];
    const float* alpha  = (const float*)d_in[3];
    const float* colors = (const float*)d_in[4];
    const float* xy     = (const float*)d_in[5];
    float* out = (float*)d_out;
    float4* gp = (float4*)d_ws;   // 1000 * 3 * 16 B = 48 KB scratch

    splat_prep<<<(NN + 255) / 256, 256, 0, stream>>>(rho, sigma, coords, alpha, colors, gp);
    // 65536 px / 64 px-per-block = 1024 blocks; 8 waves/block, one 125-chunk each
    splat_main<<<65536 / 64, 512, 0, stream>>>(gp, xy, out);
}

// Round 4
// 35.043 us; speedup vs baseline: 2.4540x; 1.0861x over previous
//
#include <hip/hip_runtime.h>
#include <math.h>

#define NN 1000
#define SPLIT 8
#define GPW 125                      /* gaussians per wave chunk */
#define BATCH 5
#define LOG2E  1.4426950408889634f
#define LN2PI  1.8378770664093453f   /* log(2*pi) */

typedef float v2f __attribute__((ext_vector_type(2)));

__device__ __forceinline__ v2f pkfma(v2f a, v2f b, v2f c) { return __builtin_elementwise_fma(a, b, c); }
__device__ __forceinline__ v2f pkmax(v2f a, v2f b)        { return __builtin_elementwise_max(a, b); }
__device__ __forceinline__ v2f splat2(float s)            { return (v2f){s, s}; }

// ---- kernel 1: per-gaussian derived params -> ws as float4[NN][3] ----
// Cholesky form: k = K - u^2 - v^2,  u = p*x + q*y + u0,  v = r*y + v0
// [0]: p, q, u0, r   [1]: v0, K, alpha, colR   [2]: colG, colB, -, -
__global__ __launch_bounds__(256) void splat_prep(
    const float* __restrict__ rho, const float* __restrict__ sigma,
    const float* __restrict__ coords, const float* __restrict__ alpha,
    const float* __restrict__ colors, float4* __restrict__ gp)
{
    int n = blockIdx.x * 256 + threadIdx.x;
    if (n >= NN) return;
    float sx = tanhf(sigma[2*n]   * 0.5f) + 1e-4f;
    float sy = tanhf(sigma[2*n+1] * 0.5f) + 1e-4f;
    float rho_a = 1.0f / (1.0f + expf(-rho[n])) + 1e-6f;   // sigmoid + EPS
    float cxx = sx*sx + 1e-6f;
    float cyy = sy*sy + 1e-6f;
    float cxy = sx*sy*rho_a;
    float det = cxx*cyy - cxy*cxy;
    float invdet = 1.0f / det;
    // M = 0.5*log2(e)*inv_cov = [[a, g],[g, b]];  M = L L^T Cholesky
    float hl = 0.5f * LOG2E;
    float a  = hl * cyy * invdet;
    float g  = -hl * cxy * invdet;
    float p  = sqrtf(a);
    float q  = g / p;
    float r  = sqrtf(hl / cyy);      // r^2 = b - q^2 = 0.5*log2e/cyy (exact algebra)
    float cx = tanhf(coords[2*n])   - 0.5f;
    float cy = tanhf(coords[2*n+1]) - 0.5f;
    float u0 = p*cx + q*cy;
    float v0 = r*cy;
    float K  = (0.5f * logf(det + 1e-6f) - LN2PI) * LOG2E;
    float al = 1.0f / (1.0f + expf(-alpha[n]));
    float cr = 1.0f / (1.0f + expf(-colors[3*n]));
    float cg = 1.0f / (1.0f + expf(-colors[3*n+1]));
    float cb = 1.0f / (1.0f + expf(-colors[3*n+2]));
    gp[3*n+0] = make_float4(p, q, u0, r);
    gp[3*n+1] = make_float4(v0, K, al, cr);
    gp[3*n+2] = make_float4(cg, cb, 0.f, 0.f);
}

// ---- kernel 2: 128 pixels/block (2 per thread, packed), 8 waves own 125-g chunks ----
__global__ __launch_bounds__(512) void splat_main(
    const float4* __restrict__ gp, const float2* __restrict__ xy2,
    float* __restrict__ out)
{
    const int tid  = threadIdx.x;
    const int wave = __builtin_amdgcn_readfirstlane(tid >> 6);
    const int lane = tid & 63;
    const int pbase = blockIdx.x * 128;
    const int p0 = pbase + lane;
    const int p1 = p0 + 64;

    float2 c0 = xy2[p0];
    float2 c1 = xy2[p1];
    const v2f X = (v2f){c0.x, c1.x};
    const v2f Y = (v2f){c0.y, c1.y};

    v2f m2 = splat2(-INFINITY);
    v2f sa = splat2(0.f), sr = splat2(0.f), sg = splat2(0.f), sb = splat2(0.f);

    const float4* gw = gp + wave * (3*GPW);   // wave-uniform base -> s_load
    for (int b = 0; b < GPW; b += BATCH) {
        float4 q0[BATCH], q1[BATCH], q2[BATCH];
        #pragma unroll
        for (int j = 0; j < BATCH; ++j) {
            q0[j] = gw[3*(b+j)+0];
            q1[j] = gw[3*(b+j)+1];
            q2[j] = gw[3*(b+j)+2];
        }
        // branch-free: k for batch (packed over 2 pixels) + batch max
        v2f k01[BATCH];
        v2f kb = splat2(-INFINITY);
        #pragma unroll
        for (int j = 0; j < BATCH; ++j) {
            v2f U = pkfma(splat2(q0[j].x), X, pkfma(splat2(q0[j].y), Y, splat2(q0[j].z)));
            v2f V = pkfma(splat2(q0[j].w), Y, splat2(q1[j].x));
            v2f k = pkfma(U, -U, pkfma(V, -V, splat2(q1[j].y)));
            k01[j] = k;
            kb = pkmax(kb, k);
        }
        // unconditional online rescale (no branch -> one basic block per batch)
        v2f mn  = pkmax(m2, kb);
        v2f dm  = m2 - mn;
        v2f s01 = (v2f){__builtin_amdgcn_exp2f(dm.x), __builtin_amdgcn_exp2f(dm.y)};
        sa *= s01; sr *= s01; sg *= s01; sb *= s01;
        m2 = mn;
        #pragma unroll
        for (int j = 0; j < BATCH; ++j) {
            v2f t = k01[j] - m2;
            v2f e = (v2f){__builtin_amdgcn_exp2f(t.x), __builtin_amdgcn_exp2f(t.y)};
            sa = pkfma(e, splat2(q1[j].z), sa);
            sr = pkfma(e, splat2(q1[j].w), sr);
            sg = pkfma(e, splat2(q2[j].x), sg);
            sb = pkfma(e, splat2(q2[j].y), sb);
        }
    }

    // ---- combine the 8 per-wave partial softmax states in LDS ----
    __shared__ float part[5][SPLIT][64][2];
    part[0][wave][lane][0] = m2.x;  part[0][wave][lane][1] = m2.y;
    part[1][wave][lane][0] = sa.x;  part[1][wave][lane][1] = sa.y;
    part[2][wave][lane][0] = sr.x;  part[2][wave][lane][1] = sr.y;
    part[3][wave][lane][0] = sg.x;  part[3][wave][lane][1] = sg.y;
    part[4][wave][lane][0] = sb.x;  part[4][wave][lane][1] = sb.y;
    __syncthreads();

    if (tid < 128) {
        const int half = tid >> 6, l = tid & 63;
        float M = part[0][0][l][half];
        #pragma unroll
        for (int w = 1; w < SPLIT; ++w) M = fmaxf(M, part[0][w][l][half]);
        float A = 0.f, R = 0.f, G = 0.f, B = 0.f;
        #pragma unroll
        for (int w = 0; w < SPLIT; ++w) {
            float s = __builtin_amdgcn_exp2f(part[0][w][l][half] - M);
            A = fmaf(part[1][w][l][half], s, A);
            R = fmaf(part[2][w][l][half], s, R);
            G = fmaf(part[3][w][l][half], s, G);
            B = fmaf(part[4][w][l][half], s, B);
        }
        float inv = 1.0f / (A + 1e-6f);
        int qx = pbase + half*64 + l;
        out[3*qx]   = R * inv;
        out[3*qx+1] = G * inv;
        out[3*qx+2] = B * inv;
    }
}

extern "C" void kernel_launch(void* const* d_in, const int* in_sizes, int n_in,
                              void* d_out, int out_size, void* d_ws, size_t ws_size,
                              hipStream_t stream) {
    const float* rho    = (const float*)d_in[0];
    const float* sigma  = (const float*)d_in[1];
    const float* coords = (const float*)d_in[2];
    const float* alpha  = (const float*)d_in[3];
    const float* colors = (const float*)d_in[4];
    const float* xy     = (const float*)d_in[5];
    float* out = (float*)d_out;
    float4* gp = (float4*)d_ws;   // 1000 * 3 * 16 B = 48 KB scratch

    splat_prep<<<(NN + 255) / 256, 256, 0, stream>>>(rho, sigma, coords, alpha, colors, gp);
    // 65536 px / 128 px-per-block = 512 blocks; 8 waves/block, one 125-chunk each
    splat_main<<<65536 / 128, 512, 0, stream>>>(gp, (const float2*)xy, out);
}

// Round 5
// 33.537 us; speedup vs baseline: 2.5642x; 1.0449x over previous
//
#include <hip/hip_runtime.h>
#include <math.h>

#define NN    1000
#define NPAD  1024                   /* padded with 24 dummy gaussians      */
#define SPLIT 8                      /* waves per block = gaussian chunks   */
#define GPW   128                    /* gaussians per wave chunk (NPAD/8)   */
#define BATCH 4
#define NB    (GPW / BATCH)          /* 32 batches per chunk                */
#define LOG2E  1.4426950408889634f
#define LN2PI  1.8378770664093453f   /* log(2*pi) */

typedef float v2f __attribute__((ext_vector_type(2)));

__device__ __forceinline__ v2f pkfma(v2f a, v2f b, v2f c) { return __builtin_elementwise_fma(a, b, c); }
__device__ __forceinline__ v2f pkmax(v2f a, v2f b)        { return __builtin_elementwise_max(a, b); }
__device__ __forceinline__ v2f splat2(float s)            { return (v2f){s, s}; }

// ---- kernel 1: per-gaussian derived params (Cholesky form), 10 dwords/g ----
// k = K - u^2 - v^2,  u = p*dx... folded:  u = p*x + q*y + u0,  v = r*y + v0
// gpA[n] = (p, q, u0, r)   gpB[n] = (v0, K, alpha, colR)   gpC[n] = (colG, colB)
__global__ __launch_bounds__(256) void splat_prep(
    const float* __restrict__ rho, const float* __restrict__ sigma,
    const float* __restrict__ coords, const float* __restrict__ alpha,
    const float* __restrict__ colors,
    float4* __restrict__ gpA, float4* __restrict__ gpB, float2* __restrict__ gpC)
{
    int n = blockIdx.x * 256 + threadIdx.x;
    if (n >= NPAD) return;
    if (n >= NN) {   // dummy: exp2(K - m) == 0 always, never raises the max
        gpA[n] = make_float4(0.f, 0.f, 0.f, 0.f);
        gpB[n] = make_float4(0.f, -1e30f, 0.f, 0.f);
        gpC[n] = make_float2(0.f, 0.f);
        return;
    }
    float sx = tanhf(sigma[2*n]   * 0.5f) + 1e-4f;
    float sy = tanhf(sigma[2*n+1] * 0.5f) + 1e-4f;
    float rho_a = 1.0f / (1.0f + expf(-rho[n])) + 1e-6f;   // sigmoid + EPS
    float cxx = sx*sx + 1e-6f;
    float cyy = sy*sy + 1e-6f;
    float cxy = sx*sy*rho_a;
    float det = cxx*cyy - cxy*cxy;
    float invdet = 1.0f / det;
    float hl = 0.5f * LOG2E;
    float a  = hl * cyy * invdet;
    float g  = -hl * cxy * invdet;
    float p  = sqrtf(a);
    float q  = g / p;
    float r  = sqrtf(hl / cyy);      // exact: b - q^2 = hl/cyy
    float cx = tanhf(coords[2*n])   - 0.5f;
    float cy = tanhf(coords[2*n+1]) - 0.5f;
    float u0 = p*cx + q*cy;
    float v0 = r*cy;
    float K  = (0.5f * logf(det + 1e-6f) - LN2PI) * LOG2E;
    float al = 1.0f / (1.0f + expf(-alpha[n]));
    float cr = 1.0f / (1.0f + expf(-colors[3*n]));
    float cg = 1.0f / (1.0f + expf(-colors[3*n+1]));
    float cb = 1.0f / (1.0f + expf(-colors[3*n+2]));
    gpA[n] = make_float4(p, q, u0, r);
    gpB[n] = make_float4(v0, K, al, cr);
    gpC[n] = make_float2(cg, cb);
}

// ---- kernel 2: 128 px/block (2/thread packed), 8 waves x 128-g chunks,
//      software-pipelined scalar loads (cur/nxt double buffer)           ----
__global__ __launch_bounds__(512) void splat_main(
    const float4* __restrict__ gpA, const float4* __restrict__ gpB,
    const float2* __restrict__ gpC, const float2* __restrict__ xy2,
    float* __restrict__ out)
{
    const int tid  = threadIdx.x;
    const int wave = __builtin_amdgcn_readfirstlane(tid >> 6);
    const int lane = tid & 63;
    const int pbase = blockIdx.x * 128;
    const int p0 = pbase + lane;
    const int p1 = p0 + 64;

    float2 c0 = xy2[p0];
    float2 c1 = xy2[p1];
    const v2f X = (v2f){c0.x, c1.x};
    const v2f Y = (v2f){c0.y, c1.y};

    v2f m2 = splat2(-INFINITY);
    v2f sa = splat2(0.f), sr = splat2(0.f), sg = splat2(0.f), sb = splat2(0.f);

    const float4* A = gpA + wave * GPW;   // wave-uniform bases -> s_load
    const float4* B = gpB + wave * GPW;
    const float2* C = gpC + wave * GPW;

    float4 cA[BATCH], cB[BATCH]; float2 cC[BATCH];
    #pragma unroll
    for (int j = 0; j < BATCH; ++j) { cA[j] = A[j]; cB[j] = B[j]; cC[j] = C[j]; }

    auto compute = [&](const float4* qA, const float4* qB, const float2* qC) {
        v2f k01[BATCH];
        v2f kb = splat2(-INFINITY);
        #pragma unroll
        for (int j = 0; j < BATCH; ++j) {
            v2f U = pkfma(splat2(qA[j].x), X, pkfma(splat2(qA[j].y), Y, splat2(qA[j].z)));
            v2f V = pkfma(splat2(qA[j].w), Y, splat2(qB[j].x));
            v2f k = pkfma(U, -U, pkfma(V, -V, splat2(qB[j].y)));
            k01[j] = k;
            kb = pkmax(kb, k);
        }
        v2f mn  = pkmax(m2, kb);               // unconditional online rescale
        v2f dm  = m2 - mn;
        v2f s01 = (v2f){__builtin_amdgcn_exp2f(dm.x), __builtin_amdgcn_exp2f(dm.y)};
        sa *= s01; sr *= s01; sg *= s01; sb *= s01;
        m2 = mn;
        #pragma unroll
        for (int j = 0; j < BATCH; ++j) {
            v2f t = k01[j] - m2;
            v2f e = (v2f){__builtin_amdgcn_exp2f(t.x), __builtin_amdgcn_exp2f(t.y)};
            sa = pkfma(e, splat2(qB[j].z), sa);
            sr = pkfma(e, splat2(qB[j].w), sr);
            sg = pkfma(e, splat2(qC[j].x), sg);
            sb = pkfma(e, splat2(qC[j].y), sb);
        }
    };

    for (int b = 0; b < NB - 1; ++b) {
        // issue next batch's scalar loads BEFORE computing current batch:
        // the mandatory lgkmcnt(0) then lands after ~160 cyc of compute.
        float4 nA[BATCH], nB[BATCH]; float2 nC[BATCH];
        const int base = (b + 1) * BATCH;
        #pragma unroll
        for (int j = 0; j < BATCH; ++j) { nA[j] = A[base+j]; nB[j] = B[base+j]; nC[j] = C[base+j]; }
        compute(cA, cB, cC);
        #pragma unroll
        for (int j = 0; j < BATCH; ++j) { cA[j] = nA[j]; cB[j] = nB[j]; cC[j] = nC[j]; }
    }
    compute(cA, cB, cC);

    // ---- combine the 8 per-wave partial softmax states in LDS ----
    __shared__ float part[5][SPLIT][64][2];
    part[0][wave][lane][0] = m2.x;  part[0][wave][lane][1] = m2.y;
    part[1][wave][lane][0] = sa.x;  part[1][wave][lane][1] = sa.y;
    part[2][wave][lane][0] = sr.x;  part[2][wave][lane][1] = sr.y;
    part[3][wave][lane][0] = sg.x;  part[3][wave][lane][1] = sg.y;
    part[4][wave][lane][0] = sb.x;  part[4][wave][lane][1] = sb.y;
    __syncthreads();

    if (tid < 128) {
        const int half = tid >> 6, l = tid & 63;
        float M = part[0][0][l][half];
        #pragma unroll
        for (int w = 1; w < SPLIT; ++w) M = fmaxf(M, part[0][w][l][half]);
        float Aa = 0.f, R = 0.f, G = 0.f, Bb = 0.f;
        #pragma unroll
        for (int w = 0; w < SPLIT; ++w) {
            float s = __builtin_amdgcn_exp2f(part[0][w][l][half] - M);
            Aa = fmaf(part[1][w][l][half], s, Aa);
            R  = fmaf(part[2][w][l][half], s, R);
            G  = fmaf(part[3][w][l][half], s, G);
            Bb = fmaf(part[4][w][l][half], s, Bb);
        }
        float inv = 1.0f / (Aa + 1e-6f);
        int qx = pbase + half*64 + l;
        out[3*qx]   = R * inv;
        out[3*qx+1] = G * inv;
        out[3*qx+2] = Bb * inv;
    }
}

extern "C" void kernel_launch(void* const* d_in, const int* in_sizes, int n_in,
                              void* d_out, int out_size, void* d_ws, size_t ws_size,
                              hipStream_t stream) {
    const float* rho    = (const float*)d_in[0];
    const float* sigma  = (const float*)d_in[1];
    const float* coords = (const float*)d_in[2];
    const float* alpha  = (const float*)d_in[3];
    const float* colors = (const float*)d_in[4];
    const float* xy     = (const float*)d_in[5];
    float* out = (float*)d_out;

    char* ws = (char*)d_ws;                       // 40 KB scratch
    float4* gpA = (float4*)(ws);
    float4* gpB = (float4*)(ws + NPAD * 16);
    float2* gpC = (float2*)(ws + NPAD * 32);

    splat_prep<<<NPAD / 256, 256, 0, stream>>>(rho, sigma, coords, alpha, colors,
                                               gpA, gpB, gpC);
    // 65536 px / 128 px-per-block = 512 blocks; 8 waves/block, one 128-chunk each
    splat_main<<<65536 / 128, 512, 0, stream>>>(gpA, gpB, gpC, (const float2*)xy, out);
}